// Round 1
// 516.011 us; speedup vs baseline: 1.0855x; 1.0855x over previous
//
#include <hip/hip_runtime.h>
#include <cstdint>
#include <math.h>

// Problem constants: B=32, TXT_T=256, MEL_T=1600, N_MEL=40
#define BB   32
#define LLEN 256
#define TLEN 1600
#define NC   40
#define NEGPADF (-1.0e12f)
#define NEGPADD (-1.0e12)
#define NBATCH 16           // DP columns per window (R8: was 8 -> half the barriers)
#define SUBB   8            // columns per producer sub-batch (reg pressure unchanged)
#define NPROD  4            // producer waves
#define NBUF   2            // LDS column buffers

#define LOG2E_F 1.4426950408889634f
#define LN2_F   0.6931471805599453f
#define C7F     1.4426950408889634e-7f  // 1e-7*log2e, folded into staged alpha lp

// Output layout (floats): mdn_loss[32] | alignment[32*1600*256] | lp[32*256*1600]
#define OFF_ALIGN 32
#define OFF_LP    (32 + (size_t)BB * TLEN * LLEN)

// Workspace (bytes): Ad double[32*256*80] | Kcd double[32*256] | lpTh float[32*1600*256]
#define WSB_A    0
#define WSB_KC   (WSB_A + (size_t)BB * LLEN * 80 * 8)
#define WSB_LPT  (WSB_KC + (size_t)BB * LLEN * 8)

__device__ __forceinline__ int imin(int a, int b) { return a < b ? a : b; }

#define WAIT_LGKM0 0xC07F   // lgkmcnt(0) only, vmcnt untouched (validated R2-R6)

// Barrier draining LDS ops only: producer's future global loads stay in flight.
__device__ __forceinline__ void bar_prod() {
  asm volatile("" ::: "memory");
  __builtin_amdgcn_s_waitcnt(WAIT_LGKM0);
  __builtin_amdgcn_s_barrier();
  asm volatile("" ::: "memory");
}
__device__ __forceinline__ void bar_cons() {
  asm volatile("" ::: "memory");
  __builtin_amdgcn_s_barrier();
  asm volatile("" ::: "memory");
}

// DPP wave-rotate-right-1: lane i <- lane i-1, lane 0 <- lane 63. VALU-only.
__device__ __forceinline__ int rot1_i32(int x) {
  return __builtin_amdgcn_mov_dpp(x, 0x13C /*wave_ror:1*/, 0xF, 0xF, true);
}
__device__ __forceinline__ float rot1_f32(float x) {
  return __int_as_float(rot1_i32(__float_as_int(x)));
}
__device__ __forceinline__ double rot1_f64(double x) {
  long long v = __double_as_longlong(x);
  int lo = rot1_i32((int)(v & 0xffffffffLL));
  int hi = rot1_i32((int)(v >> 32));
  return __longlong_as_double(((long long)hi << 32) | (unsigned long long)(unsigned int)lo);
}

// ---------------------------------------------------------------------------
// K0 (f64) [validated R2]
// ---------------------------------------------------------------------------
__global__ __launch_bounds__(256) void prep_kernel(
    const float* __restrict__ mu_logvar, double* __restrict__ A, double* __restrict__ Kc) {
  int row = blockIdx.x * 4 + (threadIdx.x >> 6);   // b*256 + l
  int lane = threadIdx.x & 63;
  const float* src = mu_logvar + (size_t)row * (2 * NC);
  double mu = 0.0, lv = 0.0, iv = 0.0, part = 0.0;
  if (lane < NC) {
    mu = (double)src[lane];
    lv = (double)src[NC + lane];
    iv = exp(-lv);
    part = mu * mu * iv + lv;
  }
  for (int m = 1; m < 64; m <<= 1) part += __shfl_xor(part, m, 64);
  const double s = -0.5 / (double)NC;
  if (lane < NC) {
    A[(size_t)row * 80 + lane]      = s * iv;
    A[(size_t)row * 80 + NC + lane] = (1.0 / (double)NC) * mu * iv;
  }
  if (lane == 0) Kc[row] = s * part;
}

// ---------------------------------------------------------------------------
// K1 (f64) [validated R2/R3/R5/R6 math]: lp + hi/lo transposed copies.
// ---------------------------------------------------------------------------
__global__ __launch_bounds__(128) void lp_kernel(
    const float* __restrict__ z, const double* __restrict__ A,
    const double* __restrict__ Kc, float* __restrict__ out,
    float* __restrict__ lpTh) {
  int b  = blockIdx.z;
  int l0 = blockIdx.y * 32;
  int t0 = blockIdx.x * 128;
  int tid = threadIdx.x;
  int t = t0 + tid;
  int tv = imin(t, TLEN - 1);
  bool act = (t < TLEN);

  float* lp_out = out + OFF_LP;
  float* loS    = out + OFF_ALIGN;   // lo scratch [b][t][l], zeroed by dp tail

  float zr[NC];
  const float* zb = z + (size_t)b * NC * TLEN;
  #pragma unroll
  for (int c = 0; c < NC; ++c) zr[c] = zb[(size_t)c * TLEN + tv];

  __shared__ __align__(16) double tile[128][17];
  const double* Ab = A + ((size_t)b * LLEN + l0) * 80;
  const double* Kb = Kc + (size_t)b * LLEN + l0;

  for (int g = 0; g < 2; ++g) {
    for (int j16 = 0; j16 < 16; ++j16) {
      int j = g * 16 + j16;
      const double* Ar = Ab + (size_t)j * 80;      // wave-uniform -> s_load
      double a0 = Kb[j], a1 = 0.0, a2 = 0.0, a3 = 0.0;
      #pragma unroll
      for (int c = 0; c < NC; c += 2) {
        double z0 = (double)zr[c], z1 = (double)zr[c + 1];
        a0 = fma(Ar[c],          z0 * z0, a0);
        a1 = fma(Ar[NC + c],     z0,      a1);
        a2 = fma(Ar[c + 1],      z1 * z1, a2);
        a3 = fma(Ar[NC + c + 1], z1,      a3);
      }
      double accd = (a0 + a2) + (a1 + a3);
      if (act) lp_out[((size_t)b * LLEN + l0 + j) * TLEN + t] = (float)accd;
      tile[tid][j16] = accd;
    }
    __syncthreads();
    #pragma unroll
    for (int p = 0; p < 4; ++p) {
      int idx = p * 128 + tid;
      int r = idx >> 2, c4 = idx & 3;
      int tr = t0 + r;
      if (tr < TLEN) {
        float h[4], lo[4];
        #pragma unroll
        for (int i = 0; i < 4; ++i) {
          double d = tile[r][c4 * 4 + i];
          float hh = (float)d;
          h[i] = hh;
          lo[i] = (float)(d - (double)hh);
        }
        size_t base = ((size_t)b * TLEN + tr) * LLEN + l0 + g * 16 + c4 * 4;
        *(float4*)(lpTh + base) = make_float4(h[0], h[1], h[2], h[3]);
        *(float4*)(loS + base)  = make_float4(lo[0], lo[1], lo[2], lo[3]);
      }
    }
    __syncthreads();
  }
}

// ---------------------------------------------------------------------------
// K2: DP, 64 blocks x 320 threads (1 consumer + 4 producer waves).
// R8 changes:
//  - NBATCH 16 (100 windows instead of 200: attack per-window fixed cost).
//    Producers keep 8-column sub-batches (2 active producers per window) so
//    register pressure & vmcnt discipline are identical to the R6 schedule.
//  - alpha DP in log2 domain (v_exp/v_log are base-2 natively); producer
//    pre-scales staged lp by log2e and folds the +1e-7 in: -12 insts/step.
//  - finalize fused: idle producer slots zero the alignment region during the
//    DP (cols < 16w are consumed; future reads >= 16w+49; clamped col-1599
//    reads feed t>=ml junk only), path lives in LDS, block-wide scatter at end.
// ---------------------------------------------------------------------------
__global__ __launch_bounds__(320, 1) void dp_kernel(
    const float* __restrict__ lpTh, const float* outR,
    const int* __restrict__ tlen, const int* __restrict__ mlen,
    float* __restrict__ out) {
  int bid = blockIdx.x;
  bool is_beta = (bid >= BB);
  int b = is_beta ? bid - BB : bid;
  int tid = threadIdx.x;
  int lane = tid & 63;
  int wv = tid >> 6;                   // 0 = consumer, 1..4 = producers
  int tl = tlen[b];
  int ml = mlen[b];
  const float* lpb = lpTh + (size_t)b * TLEN * LLEN;
  const float* lob = outR + OFF_ALIGN + (size_t)b * TLEN * LLEN;
  float* al = out + OFF_ALIGN + (size_t)b * TLEN * LLEN;
  int nint = (ml - 2 + NBATCH) / NBATCH;   // windows of 16 steps

  __shared__ __align__(16) double bufd[NBUF][NBATCH][4][64];   // beta cols, 64 KB
  __shared__ uint32_t Dbits[LLEN][TLEN / 32];                  // 51.2 KB
  __shared__ int pathL[TLEN];                                  // 6.4 KB
  float* bufaF = (float*)&bufd[0][0][0][0];   // alpha aliases bufd (disjoint blocks)

  if (wv >= 1) {
    // ---------------- producers: 8-col sub-batches, 2 active per window -----
    int q = wv - 1;
    int nsb = 2 * nint;                // sub-batch sb covers cols 1+8sb..8sb+8
    const float* ph = lpb + 4 * lane;
    const float* pl = lob + 4 * lane;
    float4 vh[SUBB], vl[SUBB];
    float4 z4 = make_float4(0.f, 0.f, 0.f, 0.f);
    auto issue = [&](int sb) {
      #pragma unroll
      for (int j = 0; j < SUBB; ++j) {
        int c = imin(1 + SUBB * sb + j, TLEN - 1);
        vh[j] = *(const float4*)(ph + (size_t)c * LLEN);
        if (is_beta) vl[j] = *(const float4*)(pl + (size_t)c * LLEN);
      }
    };
    auto store = [&](int sb) {
      int s  = (sb >> 1) % NBUF;
      int jb = (sb & 1) * SUBB;
      if (is_beta) {
        #pragma unroll
        for (int j = 0; j < SUBB; ++j) {
          bufd[s][jb + j][0][lane] = (double)vh[j].x + (double)vl[j].x;
          bufd[s][jb + j][1][lane] = (double)vh[j].y + (double)vl[j].y;
          bufd[s][jb + j][2][lane] = (double)vh[j].z + (double)vl[j].z;
          bufd[s][jb + j][3][lane] = (double)vh[j].w + (double)vl[j].w;
        }
      } else {
        #pragma unroll
        for (int j = 0; j < SUBB; ++j) {
          int off = ((s * NBATCH + jb + j) * 4) * 64 + lane;
          bufaF[off]       = fmaf(vh[j].x, LOG2E_F, C7F);
          bufaF[off + 64]  = fmaf(vh[j].y, LOG2E_F, C7F);
          bufaF[off + 128] = fmaf(vh[j].z, LOG2E_F, C7F);
          bufaF[off + 192] = fmaf(vh[j].w, LOG2E_F, C7F);
        }
      }
    };
    // prologue: window 0 (sb 0,1) staged before barrier 0; sb 2..5 in flight.
    if (q < 2) {
      issue(q); store(q);
      if (q + NPROD < nsb) issue(q + NPROD);
    } else if (q < nsb) {
      issue(q);
    }
    for (int w = 0; w < nint; ++w) {
      bar_prod();
      int sb0 = 2 * w + 2;
      int mine = ((sb0 & 3) == q) ? sb0 : ((((sb0 + 1) & 3) == q) ? (sb0 + 1) : -1);
      if (mine >= 0 && mine < nsb) {
        store(mine);                   // vmcnt wait: only own batch outstanding
        if (mine + NPROD < nsb) issue(mine + NPROD);
      }
      // fused-finalize zero-fill, hidden in the window: cols [16(w-1),16w)
      // are fully consumed (stores done, future reads >= 16w+49).
      if (is_beta && w >= 1) {
        int zc = NBATCH * (w - 1) + 4 * q;
        float* az = al + (size_t)zc * LLEN + 4 * lane;
        #pragma unroll
        for (int k = 0; k < 4; ++k) *(float4*)(az + (size_t)k * LLEN) = z4;
      }
    }
    // tail zero: cols [16(nint-1), 1600) — all loads drained (last store at
    // w = nint-2), overlaps the consumer's last window + backtrack.
    if (is_beta) {
      for (int c = NBATCH * (nint - 1) + q; c < TLEN; c += NPROD)
        *(float4*)(al + (size_t)c * LLEN + 4 * lane) = z4;
    }
  } else if (!is_beta) {
    // ---------------- consumer: forward logsumexp (f32, log2 domain) -------
    float lp00 = lpb[0] * LOG2E_F;
    float o0 = (lane == 0) ? lp00 : NEGPADF;
    float o1 = NEGPADF, o2 = NEGPADF, o3 = NEGPADF;
    float f0 = o0, f1 = o1, f2 = o2, f3 = o3;
    float qv = rot1_f32(o3);
    int t = 1;
    for (int w = 0; w < nint; ++w) {
      bar_cons();
      int s = w % NBUF;
      #pragma unroll
      for (int j = 0; j < NBATCH; ++j, ++t) {
        int off = ((s * NBATCH + j) * 4) * 64 + lane;
        float l0 = bufaF[off];
        float l1 = bufaF[off + 64];
        float l2 = bufaF[off + 128];
        float l3 = bufaF[off + 192];
        float p = (lane == 0) ? NEGPADF : qv;
        float m0 = fmaxf(o0, p),  d0 = o0 - p;
        float m1 = fmaxf(o1, o0), d1 = o1 - o0;
        float m2 = fmaxf(o2, o1), d2 = o2 - o1;
        float m3 = fmaxf(o3, o2), d3 = o3 - o2;
        // log2(2^a+2^b) = max + log2(1 + 2^-|d|); 1e-7 pre-folded into l.
        float n0 = m0 + __builtin_amdgcn_logf(1.0f + __builtin_amdgcn_exp2f(-fabsf(d0))) + l0;
        float n1 = m1 + __builtin_amdgcn_logf(1.0f + __builtin_amdgcn_exp2f(-fabsf(d1))) + l1;
        float n2 = m2 + __builtin_amdgcn_logf(1.0f + __builtin_amdgcn_exp2f(-fabsf(d2))) + l2;
        float n3 = m3 + __builtin_amdgcn_logf(1.0f + __builtin_amdgcn_exp2f(-fabsf(d3))) + l3;
        o0 = n0; o1 = n1; o2 = n2; o3 = n3;
        qv = rot1_f32(o3);
        if (t == ml - 1) { f0 = o0; f1 = o1; f2 = o2; f3 = o3; }
      }
    }
    int fr = tl - 1;
    if (lane == (fr >> 2)) {
      int sx = fr & 3;
      float val = (sx == 0) ? f0 : (sx == 1) ? f1 : (sx == 2) ? f2 : f3;
      out[b] = -val * LN2_F / (float)ml;
    }
  } else {
    // ---------------- consumer: Viterbi max-DP (f64) -----------------------
    double lp00 = (double)lpb[0] + (double)lob[0];
    double o0 = (lane == 0) ? lp00 : NEGPADD;
    double o1 = NEGPADD, o2 = NEGPADD, o3 = NEGPADD;
    uint32_t a0 = 0, a1 = (lane == 0) ? 1u : 0u, a2 = 0, a3 = 0;
    double qv = rot1_f64(o3);
    int t = 1;
    for (int w = 0; w < nint; ++w) {
      bar_cons();
      int s = w % NBUF;
      #pragma unroll
      for (int j = 0; j < NBATCH; ++j, ++t) {
        double l0 = bufd[s][j][0][lane];
        double l1 = bufd[s][j][1][lane];
        double l2 = bufd[s][j][2][lane];
        double l3 = bufd[s][j][3][lane];
        double p = (lane == 0) ? NEGPADD : qv;
        double n0 = fmax(o0, p)  + l0;
        double n1 = fmax(o1, o0) + l1;
        double n2 = fmax(o2, o1) + l2;
        double n3 = fmax(o3, o2) + l3;
        qv = rot1_f64(n3);                // row 4i-1 (mod 256) new beta
        uint32_t bit = 1u << (t & 31);
        if (qv > n0) a0 |= bit;
        if (n0 > n1) a1 |= bit;
        if (n1 > n2) a2 |= bit;
        if (n2 > n3) a3 |= bit;
        o0 = n0; o1 = n1; o2 = n2; o3 = n3;
        if ((t & 31) == 31) {
          int wd = t >> 5;
          Dbits[4 * lane + 0][wd] = a0; a0 = 0;
          Dbits[4 * lane + 1][wd] = a1; a1 = 0;
          Dbits[4 * lane + 2][wd] = a2; a2 = 0;
          Dbits[4 * lane + 3][wd] = a3; a3 = 0;
        }
      }
    }
    int tend = nint * NBATCH;            // last processed t
    int wd = tend >> 5;
    if ((tend & 31) != 31 && wd < TLEN / 32) {  // OOB guard (ml>=1594 landmine)
      Dbits[4 * lane + 0][wd] = a0;
      Dbits[4 * lane + 1][wd] = a1;
      Dbits[4 * lane + 2][wd] = a2;
      Dbits[4 * lane + 3][wd] = a3;
    }
    __builtin_amdgcn_s_waitcnt(WAIT_LGKM0);  // drain own-wave LDS writes

    // -------- literal backtrack [validated R2-R6], now into LDS ------------
    if (lane == 0) {
      int r = tl - 1;
      pathL[ml - 1] = r;
      int curR = 1 << 30, curW = -1;
      uint32_t W = 0;
      for (int qq = ml - 2; qq >= 0; --qq) {
        int w2 = qq >> 5;
        if (r >= 0 && (r != curR || w2 != curW)) { W = Dbits[r][w2]; curR = r; curW = w2; }
        int g = (r >= 0) ? (int)((W >> (qq & 31)) & 1u) : 0;
        r -= g;
        pathL[qq] = r;
      }
    }
  }

  // -------- fused finalize tail: scatter one-hots (beta blocks only) -------
  if (is_beta) {
    __syncthreads();                    // zero-fill + pathL complete
    for (int t = tid; t < ml; t += 320) {
      int p = pathL[t];
      if (p >= 0) al[(size_t)t * LLEN + p] = 1.0f;
    }
  }
}

extern "C" void kernel_launch(void* const* d_in, const int* in_sizes, int n_in,
                              void* d_out, int out_size, void* d_ws, size_t ws_size,
                              hipStream_t stream) {
  const float* mu_logvar = (const float*)d_in[0];
  const float* z         = (const float*)d_in[1];
  const int*   tlv       = (const int*)d_in[2];
  const int*   mlv       = (const int*)d_in[3];
  float* out = (float*)d_out;
  char*  wsb = (char*)d_ws;

  double* Ad   = (double*)(wsb + WSB_A);
  double* Kcd  = (double*)(wsb + WSB_KC);
  float*  lpTh = (float*)(wsb + WSB_LPT);

  prep_kernel<<<dim3(BB * LLEN / 4), 256, 0, stream>>>(mu_logvar, Ad, Kcd);
  lp_kernel<<<dim3(13, 8, BB), 128, 0, stream>>>(z, Ad, Kcd, out, lpTh);
  dp_kernel<<<dim3(2 * BB), 320, 0, stream>>>(lpTh, out, tlv, mlv, out);
}

// Round 2
// 489.620 us; speedup vs baseline: 1.1440x; 1.0539x over previous
//
#include <hip/hip_runtime.h>
#include <cstdint>
#include <math.h>

// Problem constants: B=32, TXT_T=256, MEL_T=1600, N_MEL=40
#define BB   32
#define LLEN 256
#define TLEN 1600
#define NC   40
#define NEGPADF (-1.0e12f)
#define NEGPADD (-1.0e12)
#define NBATCH 16           // DP columns per window
#define SUBB   8            // columns per producer sub-batch
#define NPROD  4            // producer waves
#define NBUF   3            // LDS column buffers (R9: store-2-ahead needs 3)

#define LOG2E_F 1.4426950408889634f
#define LN2_F   0.6931471805599453f
#define C7F     1.4426950408889634e-7f  // 1e-7*log2e, folded into staged alpha lp

// Output layout (floats): mdn_loss[32] | alignment[32*1600*256] | lp[32*256*1600]
#define OFF_ALIGN 32
#define OFF_LP    (32 + (size_t)BB * TLEN * LLEN)

// Workspace (bytes): Ad double[32*256*80] | Kcd double[32*256] | lpTh float[32*1600*256]
#define WSB_A    0
#define WSB_KC   (WSB_A + (size_t)BB * LLEN * 80 * 8)
#define WSB_LPT  (WSB_KC + (size_t)BB * LLEN * 8)

__device__ __forceinline__ int imin(int a, int b) { return a < b ? a : b; }

#define WAIT_LGKM0 0xC07F   // lgkmcnt(0) only, vmcnt untouched (validated R2-R6)

// Barrier draining LDS ops only: producer's future global loads stay in flight.
__device__ __forceinline__ void bar_prod() {
  asm volatile("" ::: "memory");
  __builtin_amdgcn_s_waitcnt(WAIT_LGKM0);
  __builtin_amdgcn_s_barrier();
  asm volatile("" ::: "memory");
}
__device__ __forceinline__ void bar_cons() {
  asm volatile("" ::: "memory");
  __builtin_amdgcn_s_barrier();
  asm volatile("" ::: "memory");
}

// DPP wave-rotate-right-1: lane i <- lane i-1, lane 0 <- lane 63. VALU-only.
__device__ __forceinline__ int rot1_i32(int x) {
  return __builtin_amdgcn_mov_dpp(x, 0x13C /*wave_ror:1*/, 0xF, 0xF, true);
}
__device__ __forceinline__ float rot1_f32(float x) {
  return __int_as_float(rot1_i32(__float_as_int(x)));
}
__device__ __forceinline__ double rot1_f64(double x) {
  long long v = __double_as_longlong(x);
  int lo = rot1_i32((int)(v & 0xffffffffLL));
  int hi = rot1_i32((int)(v >> 32));
  return __longlong_as_double(((long long)hi << 32) | (unsigned long long)(unsigned int)lo);
}

// ---------------------------------------------------------------------------
// K0 (f64) [validated R2]
// ---------------------------------------------------------------------------
__global__ __launch_bounds__(256) void prep_kernel(
    const float* __restrict__ mu_logvar, double* __restrict__ A, double* __restrict__ Kc) {
  int row = blockIdx.x * 4 + (threadIdx.x >> 6);   // b*256 + l
  int lane = threadIdx.x & 63;
  const float* src = mu_logvar + (size_t)row * (2 * NC);
  double mu = 0.0, lv = 0.0, iv = 0.0, part = 0.0;
  if (lane < NC) {
    mu = (double)src[lane];
    lv = (double)src[NC + lane];
    iv = exp(-lv);
    part = mu * mu * iv + lv;
  }
  for (int m = 1; m < 64; m <<= 1) part += __shfl_xor(part, m, 64);
  const double s = -0.5 / (double)NC;
  if (lane < NC) {
    A[(size_t)row * 80 + lane]      = s * iv;
    A[(size_t)row * 80 + NC + lane] = (1.0 / (double)NC) * mu * iv;
  }
  if (lane == 0) Kc[row] = s * part;
}

// ---------------------------------------------------------------------------
// K1 (f64) [validated R2/R3/R5/R6 math]: lp + hi/lo transposed copies.
// ---------------------------------------------------------------------------
__global__ __launch_bounds__(128) void lp_kernel(
    const float* __restrict__ z, const double* __restrict__ A,
    const double* __restrict__ Kc, float* __restrict__ out,
    float* __restrict__ lpTh) {
  int b  = blockIdx.z;
  int l0 = blockIdx.y * 32;
  int t0 = blockIdx.x * 128;
  int tid = threadIdx.x;
  int t = t0 + tid;
  int tv = imin(t, TLEN - 1);
  bool act = (t < TLEN);

  float* lp_out = out + OFF_LP;
  float* loS    = out + OFF_ALIGN;   // lo scratch [b][t][l], zeroed by dp tail

  float zr[NC];
  const float* zb = z + (size_t)b * NC * TLEN;
  #pragma unroll
  for (int c = 0; c < NC; ++c) zr[c] = zb[(size_t)c * TLEN + tv];

  __shared__ __align__(16) double tile[128][17];
  const double* Ab = A + ((size_t)b * LLEN + l0) * 80;
  const double* Kb = Kc + (size_t)b * LLEN + l0;

  for (int g = 0; g < 2; ++g) {
    for (int j16 = 0; j16 < 16; ++j16) {
      int j = g * 16 + j16;
      const double* Ar = Ab + (size_t)j * 80;      // wave-uniform -> s_load
      double a0 = Kb[j], a1 = 0.0, a2 = 0.0, a3 = 0.0;
      #pragma unroll
      for (int c = 0; c < NC; c += 2) {
        double z0 = (double)zr[c], z1 = (double)zr[c + 1];
        a0 = fma(Ar[c],          z0 * z0, a0);
        a1 = fma(Ar[NC + c],     z0,      a1);
        a2 = fma(Ar[c + 1],      z1 * z1, a2);
        a3 = fma(Ar[NC + c + 1], z1,      a3);
      }
      double accd = (a0 + a2) + (a1 + a3);
      if (act) lp_out[((size_t)b * LLEN + l0 + j) * TLEN + t] = (float)accd;
      tile[tid][j16] = accd;
    }
    __syncthreads();
    #pragma unroll
    for (int p = 0; p < 4; ++p) {
      int idx = p * 128 + tid;
      int r = idx >> 2, c4 = idx & 3;
      int tr = t0 + r;
      if (tr < TLEN) {
        float h[4], lo[4];
        #pragma unroll
        for (int i = 0; i < 4; ++i) {
          double d = tile[r][c4 * 4 + i];
          float hh = (float)d;
          h[i] = hh;
          lo[i] = (float)(d - (double)hh);
        }
        size_t base = ((size_t)b * TLEN + tr) * LLEN + l0 + g * 16 + c4 * 4;
        *(float4*)(lpTh + base) = make_float4(h[0], h[1], h[2], h[3]);
        *(float4*)(loS + base)  = make_float4(lo[0], lo[1], lo[2], lo[3]);
      }
    }
    __syncthreads();
  }
}

// ---------------------------------------------------------------------------
// K2: DP, 64 blocks x 320 threads (1 consumer + 4 producer waves).
// R9 changes (attack per-step LDS-latency stall):
//  - Producers store window w+2 during window w (NBUF=3). Window w+1's LDS is
//    complete a full window before the consumer needs it.
//  - Consumer keeps a 4-step register ring: step j consumes regs prefetched 4
//    steps ago and issues ds_reads for step j+4 (crossing into window w+1's
//    buffer for j>=12 -- legal under the store-2-ahead schedule). No lgkm(0)
//    stall at window boundaries; only counted waits for the oldest reads.
//  - Extra pre-loop barrier (-1) so the consumer can prefetch window 0.
// Race audit: during window w, consumer reads buffers w%3 / (w+1)%3; producers
// write (w+2)%3. Reads straddling bar(w+1) target (w+1)%3, next overwritten by
// stores issued during window w+2 -- after those reads were reg-consumed.
// ---------------------------------------------------------------------------
__global__ __launch_bounds__(320, 1) void dp_kernel(
    const float* __restrict__ lpTh, const float* outR,
    const int* __restrict__ tlen, const int* __restrict__ mlen,
    float* __restrict__ out) {
  int bid = blockIdx.x;
  bool is_beta = (bid >= BB);
  int b = is_beta ? bid - BB : bid;
  int tid = threadIdx.x;
  int lane = tid & 63;
  int wv = tid >> 6;                   // 0 = consumer, 1..4 = producers
  int tl = tlen[b];
  int ml = mlen[b];
  const float* lpb = lpTh + (size_t)b * TLEN * LLEN;
  const float* lob = outR + OFF_ALIGN + (size_t)b * TLEN * LLEN;
  float* al = out + OFF_ALIGN + (size_t)b * TLEN * LLEN;
  int nint = (ml - 2 + NBATCH) / NBATCH;   // windows of 16 steps

  __shared__ __align__(16) double bufd[NBUF][NBATCH][4][64];   // beta cols, 96 KB
  __shared__ uint32_t Dbits[LLEN][TLEN / 32];                  // 51.2 KB
  __shared__ int pathL[TLEN];                                  // 6.4 KB
  float* bufaF = (float*)&bufd[0][0][0][0];   // alpha aliases bufd (disjoint blocks)

  if (wv >= 1) {
    // ---------------- producers: 8-col sub-batches, store 2 windows ahead ---
    int q = wv - 1;
    int nsb = 2 * nint;                // sub-batch sb covers cols 1+8sb..8sb+8
    const float* ph = lpb + 4 * lane;
    const float* pl = lob + 4 * lane;
    float4 vh[SUBB], vl[SUBB];
    float4 z4 = make_float4(0.f, 0.f, 0.f, 0.f);
    auto issue = [&](int sb) {
      #pragma unroll
      for (int j = 0; j < SUBB; ++j) {
        int c = imin(1 + SUBB * sb + j, TLEN - 1);
        vh[j] = *(const float4*)(ph + (size_t)c * LLEN);
        if (is_beta) vl[j] = *(const float4*)(pl + (size_t)c * LLEN);
      }
    };
    auto store = [&](int sb) {
      int s  = (sb >> 1) % NBUF;
      int jb = (sb & 1) * SUBB;
      if (is_beta) {
        #pragma unroll
        for (int j = 0; j < SUBB; ++j) {
          bufd[s][jb + j][0][lane] = (double)vh[j].x + (double)vl[j].x;
          bufd[s][jb + j][1][lane] = (double)vh[j].y + (double)vl[j].y;
          bufd[s][jb + j][2][lane] = (double)vh[j].z + (double)vl[j].z;
          bufd[s][jb + j][3][lane] = (double)vh[j].w + (double)vl[j].w;
        }
      } else {
        #pragma unroll
        for (int j = 0; j < SUBB; ++j) {
          int off = ((s * NBATCH + jb + j) * 4) * 64 + lane;
          bufaF[off]       = fmaf(vh[j].x, LOG2E_F, C7F);
          bufaF[off + 64]  = fmaf(vh[j].y, LOG2E_F, C7F);
          bufaF[off + 128] = fmaf(vh[j].z, LOG2E_F, C7F);
          bufaF[off + 192] = fmaf(vh[j].w, LOG2E_F, C7F);
        }
      }
    };
    // prologue: windows 0 AND 1 (sb 0..3) staged before barrier -1;
    // sb 4..7 (windows 2,3) loads in flight.
    if (q < nsb) {
      issue(q); store(q);
      if (q + NPROD < nsb) issue(q + NPROD);
    }
    bar_prod();                        // barrier -1 (consumer prefetches win 0)
    for (int w = 0; w < nint; ++w) {
      bar_prod();
      int sb0 = 2 * w + 4;             // store window w+2
      int mine = ((sb0 & 3) == q) ? sb0 : ((((sb0 + 1) & 3) == q) ? (sb0 + 1) : -1);
      if (mine >= 0 && mine < nsb) {
        store(mine);                   // vmcnt wait: only own batch outstanding
        if (mine + NPROD < nsb) issue(mine + NPROD);
      }
      // fused-finalize zero-fill: cols [16(w-1),16w) consumed; outstanding
      // loads target cols >= 16w+33 under the store-2-ahead schedule.
      if (is_beta && w >= 1) {
        int zc = NBATCH * (w - 1) + 4 * q;
        float* az = al + (size_t)zc * LLEN + 4 * lane;
        #pragma unroll
        for (int k = 0; k < 4; ++k) *(float4*)(az + (size_t)k * LLEN) = z4;
      }
    }
    // tail zero: cols [16(nint-1), 1600) -- every producer's loads drained
    // before its bar(nint-2) arrival; this runs after bar(nint-1).
    if (is_beta) {
      for (int c = NBATCH * (nint - 1) + q; c < TLEN; c += NPROD)
        *(float4*)(al + (size_t)c * LLEN + 4 * lane) = z4;
    }
  } else if (!is_beta) {
    // ---------------- consumer: forward logsumexp (f32, log2 domain) -------
    float lp00 = lpb[0] * LOG2E_F;
    float o0 = (lane == 0) ? lp00 : NEGPADF;
    float o1 = NEGPADF, o2 = NEGPADF, o3 = NEGPADF;
    float f0 = o0, f1 = o1, f2 = o2, f3 = o3;
    float qv = rot1_f32(o3);
    bar_cons();                        // barrier -1: windows 0,1 staged
    float P[4][4];
    #pragma unroll
    for (int i = 0; i < 4; ++i) {      // prefetch window 0 steps 0..3
      const float* src = bufaF + i * 256;
      P[i][0] = src[lane]; P[i][1] = src[64 + lane];
      P[i][2] = src[128 + lane]; P[i][3] = src[192 + lane];
    }
    int t = 1;
    for (int w = 0; w < nint; ++w) {
      bar_cons();
      int s = w % NBUF, sn = (w + 1) % NBUF;
      const float* baseS = bufaF + s * (NBATCH * 256);
      const float* baseN = bufaF + sn * (NBATCH * 256);
      #pragma unroll
      for (int j = 0; j < NBATCH; ++j, ++t) {
        int rj = j & 3;
        float l0 = P[rj][0], l1 = P[rj][1], l2 = P[rj][2], l3 = P[rj][3];
        const float* src = (j < NBATCH - 4) ? (baseS + (j + 4) * 256)
                                            : (baseN + (j + 4 - NBATCH) * 256);
        P[rj][0] = src[lane];       P[rj][1] = src[64 + lane];
        P[rj][2] = src[128 + lane]; P[rj][3] = src[192 + lane];
        float p = (lane == 0) ? NEGPADF : qv;
        float m0 = fmaxf(o0, p),  d0 = o0 - p;
        float m1 = fmaxf(o1, o0), d1 = o1 - o0;
        float m2 = fmaxf(o2, o1), d2 = o2 - o1;
        float m3 = fmaxf(o3, o2), d3 = o3 - o2;
        // log2(2^a+2^b) = max + log2(1 + 2^-|d|); 1e-7 pre-folded into l.
        float n0 = m0 + __builtin_amdgcn_logf(1.0f + __builtin_amdgcn_exp2f(-fabsf(d0))) + l0;
        float n1 = m1 + __builtin_amdgcn_logf(1.0f + __builtin_amdgcn_exp2f(-fabsf(d1))) + l1;
        float n2 = m2 + __builtin_amdgcn_logf(1.0f + __builtin_amdgcn_exp2f(-fabsf(d2))) + l2;
        float n3 = m3 + __builtin_amdgcn_logf(1.0f + __builtin_amdgcn_exp2f(-fabsf(d3))) + l3;
        o0 = n0; o1 = n1; o2 = n2; o3 = n3;
        qv = rot1_f32(o3);
        if (t == ml - 1) { f0 = o0; f1 = o1; f2 = o2; f3 = o3; }
      }
    }
    int fr = tl - 1;
    if (lane == (fr >> 2)) {
      int sx = fr & 3;
      float val = (sx == 0) ? f0 : (sx == 1) ? f1 : (sx == 2) ? f2 : f3;
      out[b] = -val * LN2_F / (float)ml;
    }
  } else {
    // ---------------- consumer: Viterbi max-DP (f64) -----------------------
    double lp00 = (double)lpb[0] + (double)lob[0];
    double o0 = (lane == 0) ? lp00 : NEGPADD;
    double o1 = NEGPADD, o2 = NEGPADD, o3 = NEGPADD;
    uint32_t a0 = 0, a1 = (lane == 0) ? 1u : 0u, a2 = 0, a3 = 0;
    double qv = rot1_f64(o3);
    bar_cons();                        // barrier -1: windows 0,1 staged
    double P[4][4];
    #pragma unroll
    for (int i = 0; i < 4; ++i) {      // prefetch window 0 steps 0..3
      P[i][0] = bufd[0][i][0][lane]; P[i][1] = bufd[0][i][1][lane];
      P[i][2] = bufd[0][i][2][lane]; P[i][3] = bufd[0][i][3][lane];
    }
    int t = 1;
    for (int w = 0; w < nint; ++w) {
      bar_cons();
      int s = w % NBUF, sn = (w + 1) % NBUF;
      const double (*bs)[4][64] = bufd[s];
      const double (*bn)[4][64] = bufd[sn];
      #pragma unroll
      for (int j = 0; j < NBATCH; ++j, ++t) {
        int rj = j & 3;
        double l0 = P[rj][0], l1 = P[rj][1], l2 = P[rj][2], l3 = P[rj][3];
        {
          const double (*src)[64] = (j < NBATCH - 4) ? bs[j + 4] : bn[j + 4 - NBATCH];
          P[rj][0] = src[0][lane]; P[rj][1] = src[1][lane];
          P[rj][2] = src[2][lane]; P[rj][3] = src[3][lane];
        }
        double p = (lane == 0) ? NEGPADD : qv;
        double n0 = fmax(o0, p)  + l0;
        double n1 = fmax(o1, o0) + l1;
        double n2 = fmax(o2, o1) + l2;
        double n3 = fmax(o3, o2) + l3;
        qv = rot1_f64(n3);                // row 4i-1 (mod 256) new beta
        uint32_t bit = 1u << (t & 31);
        if (qv > n0) a0 |= bit;
        if (n0 > n1) a1 |= bit;
        if (n1 > n2) a2 |= bit;
        if (n2 > n3) a3 |= bit;
        o0 = n0; o1 = n1; o2 = n2; o3 = n3;
        if ((t & 31) == 31) {
          int wd = t >> 5;
          Dbits[4 * lane + 0][wd] = a0; a0 = 0;
          Dbits[4 * lane + 1][wd] = a1; a1 = 0;
          Dbits[4 * lane + 2][wd] = a2; a2 = 0;
          Dbits[4 * lane + 3][wd] = a3; a3 = 0;
        }
      }
    }
    int tend = nint * NBATCH;            // last processed t
    int wd = tend >> 5;
    if ((tend & 31) != 31 && wd < TLEN / 32) {  // OOB guard (ml>=1594 landmine)
      Dbits[4 * lane + 0][wd] = a0;
      Dbits[4 * lane + 1][wd] = a1;
      Dbits[4 * lane + 2][wd] = a2;
      Dbits[4 * lane + 3][wd] = a3;
    }
    __builtin_amdgcn_s_waitcnt(WAIT_LGKM0);  // drain own-wave LDS ops

    // -------- literal backtrack [validated R2-R6], into LDS ----------------
    if (lane == 0) {
      int r = tl - 1;
      pathL[ml - 1] = r;
      int curR = 1 << 30, curW = -1;
      uint32_t W = 0;
      for (int qq = ml - 2; qq >= 0; --qq) {
        int w2 = qq >> 5;
        if (r >= 0 && (r != curR || w2 != curW)) { W = Dbits[r][w2]; curR = r; curW = w2; }
        int g = (r >= 0) ? (int)((W >> (qq & 31)) & 1u) : 0;
        r -= g;
        pathL[qq] = r;
      }
    }
  }

  // -------- fused finalize tail: scatter one-hots (beta blocks only) -------
  if (is_beta) {
    __syncthreads();                    // zero-fill + pathL complete
    for (int t = tid; t < ml; t += 320) {
      int p = pathL[t];
      if (p >= 0) al[(size_t)t * LLEN + p] = 1.0f;
    }
  }
}

extern "C" void kernel_launch(void* const* d_in, const int* in_sizes, int n_in,
                              void* d_out, int out_size, void* d_ws, size_t ws_size,
                              hipStream_t stream) {
  const float* mu_logvar = (const float*)d_in[0];
  const float* z         = (const float*)d_in[1];
  const int*   tlv       = (const int*)d_in[2];
  const int*   mlv       = (const int*)d_in[3];
  float* out = (float*)d_out;
  char*  wsb = (char*)d_ws;

  double* Ad   = (double*)(wsb + WSB_A);
  double* Kcd  = (double*)(wsb + WSB_KC);
  float*  lpTh = (float*)(wsb + WSB_LPT);

  prep_kernel<<<dim3(BB * LLEN / 4), 256, 0, stream>>>(mu_logvar, Ad, Kcd);
  lp_kernel<<<dim3(13, 8, BB), 128, 0, stream>>>(z, Ad, Kcd, out, lpTh);
  dp_kernel<<<dim3(2 * BB), 320, 0, stream>>>(lpTh, out, tlv, mlv, out);
}